// Round 1
// baseline (1757.506 us; speedup 1.0000x reference)
//
#include <hip/hip_runtime.h>
#include <math.h>

#define BB 512
#define SS 16
#define HH 501
#define CC 7
#define OFF_ENC (BB*SS*SS)   // 131072 floats: dep-graph output, then node-encoding

constexpr int TM = 64, TN = 16, TK = 32;

// ---------------- G0: hiddenbuf = z @ W_lin1^T + b_lin1 ----------------
__global__ __launch_bounds__(256) void k_gemm0(
    const float* __restrict__ Am, const float* __restrict__ W0,
    const float* __restrict__ b0, float* __restrict__ out)
{
    __shared__ float As[TM][TK + 1];
    __shared__ float Ws[TN][TK + 1];
    const int tid = threadIdx.x;
    const int tx = tid & 15, ty = tid >> 4;
    const int mt = blockIdx.x >> 5, nt = blockIdx.x & 31;
    const int m0 = mt * TM, n0 = nt * TN;
    float acc[4] = {0.f, 0.f, 0.f, 0.f};
    for (int k0 = 0; k0 < HH; k0 += TK) {
#pragma unroll
        for (int i = 0; i < 8; ++i) {
            int li = tid + i * 256; int m = li >> 5, k = li & 31;
            As[m][k] = (k0 + k < HH) ? Am[(m0 + m) * HH + k0 + k] : 0.f;
        }
#pragma unroll
        for (int i = 0; i < 2; ++i) {
            int li = tid + i * 256; int n = li >> 5, k = li & 31;
            Ws[n][k] = (k0 + k < HH && n0 + n < HH) ? W0[(n0 + n) * HH + k0 + k] : 0.f;
        }
        __syncthreads();
#pragma unroll
        for (int k = 0; k < TK; ++k) {
            float w = Ws[tx][k];
#pragma unroll
            for (int i = 0; i < 4; ++i) acc[i] = fmaf(As[ty * 4 + i][k], w, acc[i]);
        }
        __syncthreads();
    }
    int r = n0 + tx;
    if (r < HH) {
#pragma unroll
        for (int i = 0; i < 4; ++i) out[(m0 + ty * 4 + i) * HH + r] = acc[i] + b0[r];
    }
}

// ---------------- per-step GRU: hout = GRUCell(x_idx, hid) ----------------
// gh = hid @ W_hh^T + b_hh (3 groups), gi = x @ W_ih^T + b_ih (K=7, inline)
__global__ __launch_bounds__(256) void k_gru(
    const float* __restrict__ hid,
    const float* __restrict__ Whh, const float* __restrict__ bhh,
    const float* __restrict__ Wih, const float* __restrict__ bih,
    const float* __restrict__ xenc, int idx,
    float* __restrict__ hout)
{
    __shared__ float As[TM][TK + 1];
    __shared__ float Ws[3][TN][TK + 1];
    const int tid = threadIdx.x;
    const int tx = tid & 15, ty = tid >> 4;
    const int mt = blockIdx.x >> 5, nt = blockIdx.x & 31;
    const int m0 = mt * TM, n0 = nt * TN;
    float acc[3][4] = {};
    for (int k0 = 0; k0 < HH; k0 += TK) {
#pragma unroll
        for (int i = 0; i < 8; ++i) {
            int li = tid + i * 256; int m = li >> 5, k = li & 31;
            As[m][k] = (k0 + k < HH) ? hid[(m0 + m) * HH + k0 + k] : 0.f;
        }
#pragma unroll
        for (int g = 0; g < 3; ++g)
#pragma unroll
            for (int i = 0; i < 2; ++i) {
                int li = tid + i * 256; int n = li >> 5, k = li & 31;
                int rr = n0 + n;
                Ws[g][n][k] = (k0 + k < HH && rr < HH) ? Whh[(g * HH + rr) * HH + k0 + k] : 0.f;
            }
        __syncthreads();
#pragma unroll
        for (int k = 0; k < TK; ++k) {
            float w0 = Ws[0][tx][k], w1 = Ws[1][tx][k], w2 = Ws[2][tx][k];
#pragma unroll
            for (int i = 0; i < 4; ++i) {
                float a = As[ty * 4 + i][k];
                acc[0][i] = fmaf(a, w0, acc[0][i]);
                acc[1][i] = fmaf(a, w1, acc[1][i]);
                acc[2][i] = fmaf(a, w2, acc[2][i]);
            }
        }
        __syncthreads();
    }
    int r = n0 + tx;
    if (r < HH) {
        float bi0 = bih[r], bi1 = bih[HH + r], bi2 = bih[2 * HH + r];
        float bh0 = bhh[r], bh1 = bhh[HH + r], bh2 = bhh[2 * HH + r];
#pragma unroll
        for (int i = 0; i < 4; ++i) {
            int b = m0 + ty * 4 + i;
            float gi0 = bi0, gi1 = bi1, gi2 = bi2;
            const float* xb = xenc + (b * SS + idx) * CC;
#pragma unroll
            for (int c = 0; c < CC; ++c) {
                float xv = xb[c];
                gi0 = fmaf(xv, Wih[(0 * HH + r) * CC + c], gi0);
                gi1 = fmaf(xv, Wih[(1 * HH + r) * CC + c], gi1);
                gi2 = fmaf(xv, Wih[(2 * HH + r) * CC + c], gi2);
            }
            float gh0 = acc[0][i] + bh0;
            float gh1 = acc[1][i] + bh1;
            float gh2 = acc[2][i] + bh2;
            float rg = 1.f / (1.f + expf(-(gi0 + gh0)));
            float ug = 1.f / (1.f + expf(-(gi1 + gh1)));
            float ng = tanhf(gi2 + rg * gh2);
            float hv = hid[b * HH + r];
            hout[b * HH + r] = (1.f - ug) * ng + ug * hv;
        }
    }
}

// ---------------- post: next-step h_in GEMM (blocks < nbf) + dots/outputs ----------------
__global__ __launch_bounds__(256) void k_post(
    const float* __restrict__ h,
    const float* __restrict__ Wgate, const float* __restrict__ bgate,
    const float* __restrict__ Wmap,  const float* __restrict__ bmap,
    const float* __restrict__ dep,
    const float* __restrict__ Wedge, const float* __restrict__ bedge,
    const float* __restrict__ Wvert, const float* __restrict__ bvert,
    int idx, int nbf,
    float* __restrict__ hiddenbuf, float* __restrict__ Alist,
    float* __restrict__ Elist, float* __restrict__ out)
{
    if ((int)blockIdx.x < nbf) {
        // h_in for step idx+1: d ? f(h_idx)+15*c0 : 16*c0
        __shared__ float As[TM][TK + 1];
        __shared__ float Ws[2][TN][TK + 1];
        const int tid = threadIdx.x;
        const int tx = tid & 15, ty = tid >> 4;
        const int mt = blockIdx.x >> 5, nt = blockIdx.x & 31;
        const int m0 = mt * TM, n0 = nt * TN;
        float acc[2][4] = {};
        for (int k0 = 0; k0 < HH; k0 += TK) {
#pragma unroll
            for (int i = 0; i < 8; ++i) {
                int li = tid + i * 256; int m = li >> 5, k = li & 31;
                As[m][k] = (k0 + k < HH) ? h[(m0 + m) * HH + k0 + k] : 0.f;
            }
#pragma unroll
            for (int g = 0; g < 2; ++g) {
                const float* Wg = (g == 0) ? Wgate : Wmap;
#pragma unroll
                for (int i = 0; i < 2; ++i) {
                    int li = tid + i * 256; int n = li >> 5, k = li & 31;
                    int rr = n0 + n;
                    Ws[g][n][k] = (k0 + k < HH && rr < HH) ? Wg[rr * HH + k0 + k] : 0.f;
                }
            }
            __syncthreads();
#pragma unroll
            for (int k = 0; k < TK; ++k) {
                float w0 = Ws[0][tx][k], w1 = Ws[1][tx][k];
#pragma unroll
                for (int i = 0; i < 4; ++i) {
                    float a = As[ty * 4 + i][k];
                    acc[0][i] = fmaf(a, w0, acc[0][i]);
                    acc[1][i] = fmaf(a, w1, acc[1][i]);
                }
            }
            __syncthreads();
        }
        int r = n0 + tx;
        if (r < HH) {
            float bg = bgate[r], bm = bmap[r];
            float c0 = (1.f / (1.f + expf(-bg))) * bm;
#pragma unroll
            for (int i = 0; i < 4; ++i) {
                int b = m0 + ty * 4 + i;
                float yg = acc[0][i] + bg;
                float ym = acc[1][i] + bm;
                float f  = (1.f / (1.f + expf(-yg))) * ym;
                float d  = dep[b * SS * SS + (idx + 1) * SS + idx];
                hiddenbuf[b * HH + r] = (d != 0.f) ? (f + 15.f * c0) : (16.f * c0);
            }
        }
    } else {
        // per-b dots: a = We[0:H].h, e = We[H:2H].h, 7 vert rows; softmax + edges
        const int j = (int)blockIdx.x - nbf;
        const int wv = threadIdx.x >> 6, lane = threadIdx.x & 63;
#pragma unroll
        for (int rep = 0; rep < 2; ++rep) {
            int b = j * 8 + wv * 2 + rep;
            float p[9] = {};
            for (int k = lane; k < HH; k += 64) {
                float hv = h[b * HH + k];
                p[0] = fmaf(Wedge[k], hv, p[0]);
                p[1] = fmaf(Wedge[HH + k], hv, p[1]);
#pragma unroll
                for (int c = 0; c < CC; ++c) p[2 + c] = fmaf(Wvert[c * HH + k], hv, p[2 + c]);
            }
#pragma unroll
            for (int off = 32; off > 0; off >>= 1)
#pragma unroll
                for (int q = 0; q < 9; ++q) p[q] += __shfl_down(p[q], off, 64);
            if (lane == 0) {
                if (idx >= 0) { Alist[idx * BB + b] = p[0]; Elist[idx * BB + b] = p[1]; }
                if (idx <= SS - 2) {
                    float lv[CC]; float mx = -1e30f;
                    for (int c = 0; c < CC; ++c) { lv[c] = p[2 + c] + bvert[c]; mx = fmaxf(mx, lv[c]); }
                    float ev[CC]; float sum = 0.f;
                    for (int c = 0; c < CC; ++c) { ev[c] = expf(lv[c] - mx); sum += ev[c]; }
                    float inv = 1.f / sum;
                    for (int c = 0; c < CC; ++c)
                        out[OFF_ENC + (b * SS + (idx + 1)) * CC + c] = ev[c] * inv;
                }
                if (idx >= 1) {
                    float be = bedge[0];
                    float aprev = Alist[(idx - 1) * BB + b], eprev = Elist[(idx - 1) * BB + b];
                    // t=0 edge: hv = h_{idx-1}, hidden_j = h_{idx-1}
                    out[b * SS * SS + idx * SS + (idx - 1)] = (aprev + eprev + be >= 0.f) ? 1.f : 0.f;
                    float acur = p[0]; // a(h_idx)
                    for (int vj = 0; vj <= idx - 2; ++vj)
                        out[b * SS * SS + idx * SS + vj] =
                            (acur + Elist[vj * BB + b] + be >= 0.f) ? 1.f : 0.f;
                }
            }
        }
    }
}

extern "C" void kernel_launch(void* const* d_in, const int* in_sizes, int n_in,
                              void* d_out, int out_size, void* d_ws, size_t ws_size,
                              hipStream_t stream)
{
    const float* z     = (const float*)d_in[0];
    const float* dep   = (const float*)d_in[1];
    const float* xenc  = (const float*)d_in[2];
    const float* Wlin1 = (const float*)d_in[3];
    const float* blin1 = (const float*)d_in[4];
    const float* Wvert = (const float*)d_in[5];
    const float* bvert = (const float*)d_in[6];
    const float* Wedge = (const float*)d_in[7];
    const float* bedge = (const float*)d_in[8];
    const float* Wgate = (const float*)d_in[9];
    const float* bgate = (const float*)d_in[10];
    const float* Wmap  = (const float*)d_in[11];
    const float* bmap  = (const float*)d_in[12];
    const float* Wih   = (const float*)d_in[13];
    const float* bih   = (const float*)d_in[14];
    const float* Whh   = (const float*)d_in[15];
    const float* bhh   = (const float*)d_in[16];
    float* out = (float*)d_out;

    float* ws = (float*)d_ws;
    float* hiddenbuf = ws;                 // B*H (GRU hidden input / g0)
    float* hbuf      = ws + BB * HH;       // B*H (current h)
    float* Alist     = ws + 2 * BB * HH;   // 16*B
    float* Elist     = Alist + SS * BB;    // 16*B

    // dep-graph output: only cols < idx of row idx get written; rest must be 0
    hipMemsetAsync(d_out, 0, (size_t)OFF_ENC * sizeof(float), stream);

    k_gemm0<<<256, 256, 0, stream>>>(z, Wlin1, blin1, hiddenbuf);
    // logits row 0 from g0 (no edges, no a/e, no f-GEMM)
    k_post<<<64, 256, 0, stream>>>(hiddenbuf, Wgate, bgate, Wmap, bmap, dep,
                                   Wedge, bedge, Wvert, bvert, -1, 0,
                                   hiddenbuf, Alist, Elist, out);
    for (int idx = 0; idx < SS; ++idx) {
        k_gru<<<256, 256, 0, stream>>>(hiddenbuf, Whh, bhh, Wih, bih, xenc, idx, hbuf);
        int nbf = (idx < SS - 1) ? 256 : 0;
        k_post<<<nbf + 64, 256, 0, stream>>>(hbuf, Wgate, bgate, Wmap, bmap, dep,
                                             Wedge, bedge, Wvert, bvert, idx, nbf,
                                             hiddenbuf, Alist, Elist, out);
    }
}